// Round 5
// baseline (110.630 us; speedup 1.0000x reference)
//
#include <hip/hip_runtime.h>

// B=16, S=4096, D=1024, H=16, K=15, DK=64
constexpr int Bc   = 16;
constexpr int Sc   = 4096;
constexpr int Hc   = 16;
constexpr int Kc   = 15;
constexpr int DKc  = 64;
constexpr int ROWS = 32;        // rows per block (8 threads/row, 8 outputs/thread)
constexpr int THREADS = 256;

typedef float f32x4 __attribute__((ext_vector_type(4)));

__global__ __launch_bounds__(THREADS) void lwconv_kernel(
    const float* __restrict__ x, const float* __restrict__ W,
    const float* __restrict__ bias, float* __restrict__ out)
{
    const int tid = threadIdx.x;
    const long long row0 = (long long)blockIdx.x * ROWS;

    // block-uniform decode: rid = (b*H + h)*S + s'   (ROWS=32 divides 4096 -> h,b uniform)
    const int h    = (int)((row0 >> 12) & (Hc - 1));
    const int bidx = (int)(row0 >> 16);
    const long long sp0 = row0 & (Sc - 1);

    // softmax(W[h]); 1/sum folded into taps, bias as accumulator init (h block-uniform -> SGPR)
    float w[Kc];
    float wmax = -1e30f;
    #pragma unroll
    for (int t = 0; t < Kc; ++t) { w[t] = W[h * Kc + t]; wmax = fmaxf(wmax, w[t]); }
    float wsum = 0.f;
    #pragma unroll
    for (int t = 0; t < Kc; ++t) { w[t] = __expf(w[t] - wmax); wsum += w[t]; }
    const float winv = 1.f / wsum;
    #pragma unroll
    for (int t = 0; t < Kc; ++t) w[t] *= winv;
    const float bv = bias[h];

    const long long in_base  = row0 * DKc;
    const long long out_base = ((long long)(h * Bc + bidx) * Sc + sp0) * DKc;
    const long long Ntot     = (long long)Bc * Hc * Sc * DKc;
    const bool interior = (blockIdx.x != 0) && (blockIdx.x != gridDim.x - 1);

    const f32x4* __restrict__ xv = (const f32x4*)x;
    f32x4* outv = (f32x4*)(out + out_base);

    const int r  = tid >> 3;            // row within block [0,32)
    const int c0 = (tid & 7) * 8;       // starting column of this thread's 8 outputs
    // window f[j] = x_row[c0 - 8 + j], j = 0..23 (6 quads, all 16B-aligned)
    const float mF = (c0 != 0)  ? 1.f : 0.f;   // f[0..7]  : cols c0-8..c0-1
    const float mB = (c0 != 56) ? 1.f : 0.f;   // f[16..23]: cols c0+8..c0+15

    const long long off = in_base + (long long)r * DKc + c0 - 8;   // float idx, %4==0
    float f[24];
    if (interior) {
        #pragma unroll
        for (int i = 0; i < 6; ++i)
            *(f32x4*)&f[4 * i] = xv[(off >> 2) + i];
    } else {
        #pragma unroll
        for (int i = 0; i < 6; ++i) {
            long long o = off + 4 * i;
            f32x4 v = (f32x4)(0.f);
            if (o >= 0 && o + 4 <= Ntot) v = xv[o >> 2];
            *(f32x4*)&f[4 * i] = v;
        }
    }
    #pragma unroll
    for (int j = 0; j < 8; ++j)  f[j]      *= mF;
    #pragma unroll
    for (int j = 16; j < 24; ++j) f[j]     *= mB;

    float a[8];
    #pragma unroll
    for (int o = 0; o < 8; ++o) a[o] = bv;
    #pragma unroll
    for (int t = 0; t < Kc; ++t) {            // out[c0+o] uses f[o+1+t]
        #pragma unroll
        for (int o = 0; o < 8; ++o)
            a[o] = fmaf(w[t], f[o + 1 + t], a[o]);
    }

    f32x4 q0, q1;
    q0.x = fmaxf(a[0], 0.f); q0.y = fmaxf(a[1], 0.f);
    q0.z = fmaxf(a[2], 0.f); q0.w = fmaxf(a[3], 0.f);
    q1.x = fmaxf(a[4], 0.f); q1.y = fmaxf(a[5], 0.f);
    q1.z = fmaxf(a[6], 0.f); q1.w = fmaxf(a[7], 0.f);
    const int g = (r * DKc + c0) >> 2;        // output quad index within block span
    __builtin_nontemporal_store(q0, &outv[g]);
    __builtin_nontemporal_store(q1, &outv[g + 1]);
}

extern "C" void kernel_launch(void* const* d_in, const int* in_sizes, int n_in,
                              void* d_out, int out_size, void* d_ws, size_t ws_size,
                              hipStream_t stream) {
    const float* x    = (const float*)d_in[0];
    const float* W    = (const float*)d_in[1];
    const float* bias = (const float*)d_in[2];
    float* out        = (float*)d_out;

    const long long total_rows = (long long)Bc * Hc * Sc;   // 1,048,576
    const int grid = (int)(total_rows / ROWS);              // 32,768
    lwconv_kernel<<<grid, THREADS, 0, stream>>>(x, W, bias, out);
}

// Round 6
// 87.644 us; speedup vs baseline: 1.2623x; 1.2623x over previous
//
#include <hip/hip_runtime.h>

// B=16, S=4096, D=1024, H=16, K=15, DK=64
constexpr int Bc   = 16;
constexpr int Sc   = 4096;
constexpr int Hc   = 16;
constexpr int Kc   = 15;
constexpr int DKc  = 64;
constexpr int ROWS = 64;        // rows per block
constexpr int THREADS = 256;

typedef float f32x4 __attribute__((ext_vector_type(4)));

__global__ __launch_bounds__(THREADS) void lwconv_kernel(
    const float* __restrict__ x, const float* __restrict__ W,
    const float* __restrict__ bias, float* __restrict__ out)
{
    const int tid = threadIdx.x;
    const long long row0 = (long long)blockIdx.x * ROWS;

    // block-uniform decode: rid = (b*H + h)*S + s'
    const int h    = (int)((row0 >> 12) & (Hc - 1));
    const int bidx = (int)(row0 >> 16);
    const long long sp0 = row0 & (Sc - 1);

    // softmax(W[h]); 1/sum folded into taps, bias as accumulator init (scalarizes: h uniform)
    float w[Kc];
    float wmax = -1e30f;
    #pragma unroll
    for (int t = 0; t < Kc; ++t) { w[t] = W[h * Kc + t]; wmax = fmaxf(wmax, w[t]); }
    float wsum = 0.f;
    #pragma unroll
    for (int t = 0; t < Kc; ++t) { w[t] = __expf(w[t] - wmax); wsum += w[t]; }
    const float winv = 1.f / wsum;
    #pragma unroll
    for (int t = 0; t < Kc; ++t) w[t] *= winv;
    const float bv = bias[h];

    const long long in_base  = row0 * DKc;                                  // float idx
    const long long out_base = ((long long)(h * Bc + bidx) * Sc + sp0) * DKc;
    const long long Ntot     = (long long)Bc * Hc * Sc * DKc;               // 67.1M floats
    const bool interior = (blockIdx.x != 0) && (blockIdx.x != gridDim.x - 1);

    const f32x4* __restrict__ xv = (const f32x4*)x;   // all window offsets are 16B-aligned
    f32x4* outv = (f32x4*)(out + out_base);

    // c0 = starting column of this thread's 4 outputs; loop-invariant (256 % 16 == 0)
    const int c0 = (tid & 15) * 4;
    // window element f[j] holds column c0-8+j; zero-mask out-of-row groups (quad-aligned)
    const float mA = (c0 >= 8)  ? 1.f : 0.f;   // f[0..3]  : cols c0-8..c0-5
    const float mB = (c0 >= 4)  ? 1.f : 0.f;   // f[4..7]  : cols c0-4..c0-1
    const float mC = (c0 <= 56) ? 1.f : 0.f;   // f[12..15]: cols c0+4..c0+7
    const float mD = (c0 <= 52) ? 1.f : 0.f;   // f[16..19]: cols c0+8..c0+11

    #pragma unroll
    for (int j = 0; j < 4; ++j) {
        const int g = j * THREADS + tid;            // float4 unit [0,1024)
        const int r = g >> 4;                       // row within block
        const long long off = in_base + (long long)r * DKc + c0 - 8;  // %4 == 0
        float f[20];
        if (interior) {
            #pragma unroll
            for (int i = 0; i < 5; ++i)
                *(f32x4*)&f[4 * i] = xv[(off >> 2) + i];
        } else {
            #pragma unroll
            for (int i = 0; i < 5; ++i) {
                long long o = off + 4 * i;
                f32x4 v = (f32x4)(0.f);
                if (o >= 0 && o + 4 <= Ntot) v = xv[o >> 2];
                *(f32x4*)&f[4 * i] = v;
            }
        }
        f[0]  *= mA; f[1]  *= mA; f[2]  *= mA; f[3]  *= mA;
        f[4]  *= mB; f[5]  *= mB; f[6]  *= mB; f[7]  *= mB;
        f[12] *= mC; f[13] *= mC; f[14] *= mC; f[15] *= mC;
        f[16] *= mD; f[17] *= mD; f[18] *= mD; f[19] *= mD;

        float a0 = bv, a1 = bv, a2 = bv, a3 = bv;
        #pragma unroll
        for (int t = 0; t < Kc; ++t) {              // out[c0+o] uses f[o+1+t]
            a0 = fmaf(w[t], f[1 + t], a0);
            a1 = fmaf(w[t], f[2 + t], a1);
            a2 = fmaf(w[t], f[3 + t], a2);
            a3 = fmaf(w[t], f[4 + t], a3);
        }
        f32x4 o4;
        o4.x = fmaxf(a0, 0.f); o4.y = fmaxf(a1, 0.f);
        o4.z = fmaxf(a2, 0.f); o4.w = fmaxf(a3, 0.f);
        __builtin_nontemporal_store(o4, &outv[g]);  // zero-reuse output: don't thrash L2
    }
}

extern "C" void kernel_launch(void* const* d_in, const int* in_sizes, int n_in,
                              void* d_out, int out_size, void* d_ws, size_t ws_size,
                              hipStream_t stream) {
    const float* x    = (const float*)d_in[0];
    const float* W    = (const float*)d_in[1];
    const float* bias = (const float*)d_in[2];
    float* out        = (float*)d_out;

    const long long total_rows = (long long)Bc * Hc * Sc;   // 1,048,576
    const int grid = (int)(total_rows / ROWS);              // 16,384
    lwconv_kernel<<<grid, THREADS, 0, stream>>>(x, W, bias, out);
}